// Round 3
// baseline (195.430 us; speedup 1.0000x reference)
//
#include <hip/hip_runtime.h>

// plane_rotations: the reference's _build_mat annihilates all rows except
// (i,j) at every scan step (jnp.zeros_like, not eye). After the (0,*) block
// only rows {0,127} survive; step (1,2) reads two all-zero rows, sets rows
// 1,2 to zero and annihilates the rest -> mat becomes exactly 0 and stays 0
// (finite * 0 == 0 bit-exact in fp32). Output = x @ 0^T = exact zeros.
// Task = zero-fill the output. hipMemsetAsync is graph-capturable and
// byte 0x00 == fp32 0.
//
// SIZE SEMANTICS (settled by round-0/1 A/B): out_size is the ELEMENT count
// (33,554,432 floats = 128 MiB output). Evidence:
//  - Shrinking our memset from out_size*4 to out_size bytes moved dur_us by
//    -14.4 us == (128 MiB - 32 MiB) / 6.7 TB/s. Byte-count semantics would
//    have predicted -60 us. Element-count fits exactly.
//  - The 512-MiB / ~80 us fillBufferAligned dispatches in the profile are
//    HARNESS poison/reset fills: they stayed at 524288 KB across both rounds
//    while our memset size changed 4x, so they are not our node.
// Round 1's out_size-bytes memset therefore zeroed only 1/4 of the output
// and passed only because the remaining 96 MiB was already zero (stale
// zeros / fresh pages) -- the re-poison-semantics trap. Full fill restored:
//
//   bytes = out_size * sizeof(float) = 134,217,728 B  (~20 us @ 6.7 TB/s)
//
// The rest of dur_us (~175 us) is harness-side work inside the timed region
// (512-MiB poison fill, input restore, launch overhead) and is not reachable
// from kernel_launch. Our controllable portion runs at ~84% of HBM peak via
// the vendor fill path -- at the write roofline.
//
// Round 2 note: the round-2 submission of this exact source failed with
// "MI355X container failed twice" (broker infrastructure, no compile/test
// output) -- resubmitting unchanged.

extern "C" void kernel_launch(void* const* d_in, const int* in_sizes, int n_in,
                              void* d_out, int out_size, void* d_ws,
                              size_t ws_size, hipStream_t stream) {
  (void)d_in; (void)in_sizes; (void)n_in; (void)d_ws; (void)ws_size;
  hipMemsetAsync(d_out, 0, (size_t)out_size * sizeof(float), stream);
}